// Round 11
// baseline (120.513 us; speedup 1.0000x reference)
//
#include <hip/hip_runtime.h>
#include <hip/hip_bf16.h>

#define NB 4
#define NQ 32768
#define NHW 65536
#define NTOK (NB * NQ)

typedef __attribute__((ext_vector_type(8))) short short8;   // 8 bf16 = 4 VGPR (MFMA A/B frag)
typedef __attribute__((ext_vector_type(4))) float f32x4;    // MFMA C/D frag
typedef __attribute__((ext_vector_type(2))) float f32x2;    // packed-f32 pair (even-aligned VGPR pair)

// VOP3P packed f32: op_sel selects src half for LOW result, op_sel_hi for HIGH result.
// *_LO broadcasts the LOW half of src b to both result halves; *_HI broadcasts the HIGH half.
#define PKMUL_LO(dst, a, b) asm("v_pk_mul_f32 %0, %1, %2 op_sel:[0,0] op_sel_hi:[1,0]" : "=v"(dst) : "v"(a), "v"(b))
#define PKMUL_HI(dst, a, b) asm("v_pk_mul_f32 %0, %1, %2 op_sel:[0,1] op_sel_hi:[1,1]" : "=v"(dst) : "v"(a), "v"(b))
#define PKFMA_LO(acc, a, b) asm("v_pk_fma_f32 %0, %1, %2, %0 op_sel:[0,0,0] op_sel_hi:[1,0,1]" : "+v"(acc) : "v"(a), "v"(b))
#define PKFMA_HI(acc, a, b) asm("v_pk_fma_f32 %0, %1, %2, %0 op_sel:[0,1,0] op_sel_hi:[1,1,1]" : "+v"(acc) : "v"(a), "v"(b))

__device__ __forceinline__ unsigned short f2bf(float f) {
    unsigned int u = __float_as_uint(f);
    u = (u + 0x7FFFu + ((u >> 16) & 1u)) >> 16;   // RNE
    return (unsigned short)u;
}

__device__ __forceinline__ float bflo(unsigned int u) { return __uint_as_float(u << 16); }
__device__ __forceinline__ float bfhi(unsigned int u) { return __uint_as_float(u & 0xffff0000u); }

__device__ __forceinline__ float gelu_tanh(float u) {
    float z = 0.7978845608028654f * (u + 0.044715f * u * u * u);
    float e = __expf(2.0f * z);
    return u - u / (e + 1.0f);   // 0.5*u*(1+tanh(z)), overflow-safe
}

// (B,C,H,W) f32 -> (B,H*W,64) bf16, channel-permuted: chan c -> position p = 4*(c&15) + (c>>4)
__global__ __launch_bounds__(256) void feat_transpose_kernel(
        const float* __restrict__ feat, unsigned int* __restrict__ featT) {
    __shared__ float tile[64][65];
    int blk = blockIdx.x;
    int b = blk >> 10;
    int hw0 = (blk & 1023) << 6;
    int lane = threadIdx.x & 63;
    int row = threadIdx.x >> 6;
    const float* src = feat + ((size_t)b * 64) * NHW + hw0;
    #pragma unroll
    for (int cc = 0; cc < 16; ++cc) {
        int c = (cc << 2) + row;
        tile[c][lane] = src[(size_t)c * NHW + lane];
    }
    __syncthreads();
    unsigned int* dst = featT + ((size_t)(b * NHW + hw0)) * 32;
    #pragma unroll
    for (int it = 0; it < 8; ++it) {
        int flat = it * 256 + threadIdx.x;
        int w = flat >> 5, pp = flat & 31;        // u32 pp covers positions 2pp,2pp+1
        int c1 = (pp >> 1) + 32 * (pp & 1);       // chan of lo; hi chan = c1+16
        unsigned int u;
        asm("v_cvt_pk_bf16_f32 %0, %1, %2" : "=v"(u) : "v"(tile[c1][w]), "v"(tile[c1 + 16][w]));
        dst[(size_t)w * 32 + pp] = u;
    }
}

// Pack 6 weight matrices (64x64 f32 [k][n]) into bf16 B-fragment order with the
// k' permutation: k' = p, original k = (p&3)*16 + (p>>2).
__global__ __launch_bounds__(64) void wprep_kernel(
        const float* __restrict__ wq, const float* __restrict__ wk,
        const float* __restrict__ wv, const float* __restrict__ wo,
        const float* __restrict__ wm1, const float* __restrict__ wm2,
        unsigned short* __restrict__ out) {
    int bid = blockIdx.x;               // 48
    int mat = bid >> 3, ti = bid & 7;
    int kt = ti >> 2, nt = ti & 3;
    int l = threadIdx.x;
    const float* W = (mat == 0) ? wq : (mat == 1) ? wk : (mat == 2) ? wv
                   : (mat == 3) ? wo : (mat == 4) ? wm1 : wm2;
    unsigned short* dst = out + ((size_t)(bid) * 64 + l) * 8;
    #pragma unroll
    for (int j = 0; j < 8; ++j) {
        int kp = 8 * (l >> 4) + j + 32 * kt;       // permuted k'
        int k = ((kp & 3) << 4) + (kp >> 2);       // original chan
        int n = (l & 15) + 16 * nt;
        dst[j] = f2bf(W[k * 64 + n]);
    }
}

// One wave = 4 tokens (M=16 rows). Lane = (g = lane>>4 token, li = lane&15).
// D-layout: lane holds rows 4g+i, chans li+16*nt (staged at k'-pos 4li+nt).
// Per-wave LDS 10KB: [0,2KB) A-frag staging bf16 (aliases Q attn staging),
//                    [2KB,6KB) K staging f32, [6KB,10KB) V staging f32.
template<bool USE_T>
__global__ __launch_bounds__(256, 2) void token_kernel(
    const float* __restrict__ depth, const float* __restrict__ feat,
    const unsigned int* __restrict__ featT, const float* __restrict__ coord,
    const float* __restrict__ w_ce, const float* __restrict__ b_ce,
    const float* __restrict__ ln1_g, const float* __restrict__ ln1_b,
    const float* __restrict__ b_o, const float* __restrict__ ln2_g,
    const float* __restrict__ ln2_b, const float* __restrict__ b_m1,
    const float* __restrict__ b_m2, const float* __restrict__ w_head,
    const unsigned short* __restrict__ wprep, float* __restrict__ out)
{
    __shared__ char smem[4 * 10240];
    const int wid = threadIdx.x >> 6;
    const int lane = threadIdx.x & 63;
    const int g = lane >> 4;
    const int li = lane & 15;
    const int n = ((blockIdx.x << 2) + wid) * 4 + g;
    const int b = n >> 15;
    char* sb = smem + wid * 10240;

    // ---- distributed gather: each lane computes ONE shifted-coord variant ----
    const float cy0 = coord[2 * n], cx0 = coord[2 * n + 1];
    float relv0, relv1, predv;
    int linv;
    {
        int v = li & 3;
        float vx = (v < 2) ? -1.0f : 1.0f;
        float vy = (v & 1) ? 1.0f : -1.0f;
        float cy = fminf(fmaxf(cy0 + vx * 0.00390625f + 1e-6f, -1.0f + 1e-6f), 1.0f - 1e-6f);
        float cx = fminf(fmaxf(cx0 + vy * 0.00390625f + 1e-6f, -1.0f + 1e-6f), 1.0f - 1e-6f);
        int iy = min(max((int)rintf((cy + 1.0f) * 128.0f - 0.5f), 0), 255);
        int ix = min(max((int)rintf((cx + 1.0f) * 128.0f - 0.5f), 0), 255);
        linv = iy * 256 + ix;
        predv = depth[(b << 16) + linv];
        float ysy = -0.99609375f + 0.0078125f * (float)iy;
        float xsx = -0.99609375f + 0.0078125f * (float)ix;
        relv0 = (cy0 - ysy) * 256.0f;
        relv1 = (cx0 - xsx) * 256.0f;
    }
    const int gbase = lane & 48;     // 16*g

    float wce0[4], wce1[4], bce[4];
    #pragma unroll
    for (int j = 0; j < 4; ++j) {
        wce0[j] = w_ce[li + 16 * j]; wce1[j] = w_ce[64 + li + 16 * j]; bce[j] = b_ce[li + 16 * j];
    }
    float x[4][4];
    #pragma unroll
    for (int i = 0; i < 4; ++i) {
        int lin = __shfl(linv, gbase + i, 64);
        float rel0 = __shfl(relv0, gbase + i, 64);
        float rel1 = __shfl(relv1, gbase + i, 64);
        float t0, t1, t2, t3;
        if (USE_T) {
            uint2 w = *(const uint2*)(featT + ((size_t)((b << 16) + lin)) * 32 + 2 * li);
            t0 = bflo(w.x); t1 = bfhi(w.x); t2 = bflo(w.y); t3 = bfhi(w.y);
        } else {
            t0 = feat[(((size_t)(b * 64 + li)) << 16) + lin];
            t1 = feat[(((size_t)(b * 64 + li + 16)) << 16) + lin];
            t2 = feat[(((size_t)(b * 64 + li + 32)) << 16) + lin];
            t3 = feat[(((size_t)(b * 64 + li + 48)) << 16) + lin];
        }
        x[i][0] = t0 + rel0 * wce0[0] + rel1 * wce1[0] + bce[0];
        x[i][1] = t1 + rel0 * wce0[1] + rel1 * wce1[1] + bce[1];
        x[i][2] = t2 + rel0 * wce0[2] + rel1 * wce1[2] + bce[2];
        x[i][3] = t3 + rel0 * wce0[3] + rel1 * wce1[3] + bce[3];
    }

    // ---- helpers ----
    auto lnorm = [&](float xv[4][4], float hv[4][4],
                     const float* __restrict__ gp, const float* __restrict__ bp) {
        float gj[4], bj[4];
        #pragma unroll
        for (int j = 0; j < 4; ++j) { gj[j] = gp[li + 16 * j]; bj[j] = bp[li + 16 * j]; }
        #pragma unroll
        for (int i = 0; i < 4; ++i) {
            float s = xv[i][0] + xv[i][1] + xv[i][2] + xv[i][3];
            float ss = xv[i][0] * xv[i][0] + xv[i][1] * xv[i][1]
                     + xv[i][2] * xv[i][2] + xv[i][3] * xv[i][3];
            #pragma unroll
            for (int m = 1; m < 16; m <<= 1) {
                s += __shfl_xor(s, m, 64);
                ss += __shfl_xor(ss, m, 64);
            }
            float mean = s * 0.015625f;
            float var = ss * 0.015625f - mean * mean;
            float rs = rsqrtf(var + 1e-5f);
            #pragma unroll
            for (int j = 0; j < 4; ++j)
                hv[i][j] = (xv[i][j] - mean) * rs * gj[j] + bj[j];
        }
    };

    auto put16 = [&](const float v[4][4]) {
        #pragma unroll
        for (int i = 0; i < 4; ++i) {
            int r = 4 * g + i;
            unsigned int u0, u1;
            asm("v_cvt_pk_bf16_f32 %0, %1, %2" : "=v"(u0) : "v"(v[i][0]), "v"(v[i][1]));
            asm("v_cvt_pk_bf16_f32 %0, %1, %2" : "=v"(u1) : "v"(v[i][2]), "v"(v[i][3]));
            *(uint2*)(sb + 128 * r + 16 * (((li >> 1)) ^ (r & 7)) + 8 * (li & 1))
                = make_uint2(u0, u1);
        }
        asm volatile("s_waitcnt lgkmcnt(0)" ::: "memory");
    };
    auto get_frags = [&](short8& a0, short8& a1) {
        a0 = *(const short8*)(sb + 128 * li + 16 * (g ^ (li & 7)));
        a1 = *(const short8*)(sb + 128 * li + 16 * ((4 + g) ^ (li & 7)));
    };

    auto gemm = [&](short8 a0, short8 a1, const short8* __restrict__ Wf, f32x4 acc[4]) {
        #pragma unroll
        for (int nt = 0; nt < 4; ++nt) {
            acc[nt] = __builtin_amdgcn_mfma_f32_16x16x32_bf16(a0, Wf[nt * 64 + lane], acc[nt], 0, 0, 0);
            acc[nt] = __builtin_amdgcn_mfma_f32_16x16x32_bf16(a1, Wf[(4 + nt) * 64 + lane], acc[nt], 0, 0, 0);
        }
    };

    const short8* Wq  = (const short8*)(wprep);
    const short8* Wk  = (const short8*)(wprep + 1 * 4096);
    const short8* Wv  = (const short8*)(wprep + 2 * 4096);
    const short8* Wo  = (const short8*)(wprep + 3 * 4096);
    const short8* Wm1 = (const short8*)(wprep + 4 * 4096);
    const short8* Wm2 = (const short8*)(wprep + 5 * 4096);
    const f32x4 z4 = {0.0f, 0.0f, 0.0f, 0.0f};

    // ---- LN1 + QKV ----
    float h[4][4];
    lnorm(x, h, ln1_g, ln1_b);
    short8 a0, a1;
    put16(h);
    get_frags(a0, a1);
    f32x4 qa[4], ka[4], va[4];
    #pragma unroll
    for (int t = 0; t < 4; ++t) { qa[t] = z4; ka[t] = z4; va[t] = z4; }
    gemm(a0, a1, Wq, qa);
    gemm(a0, a1, Wk, ka);
    gemm(a0, a1, Wv, va);

    // ---- attention staging: Q bf16 (aliases A-frag region), K/V f32 ----
    #pragma unroll
    for (int nt = 0; nt < 4; ++nt) {
        int q = 4 * g + nt;
        int xr = li ^ (q & 7);
        unsigned int uq0, uq1;
        asm("v_cvt_pk_bf16_f32 %0, %1, %2" : "=v"(uq0) : "v"(qa[nt][0]), "v"(qa[nt][1]));
        asm("v_cvt_pk_bf16_f32 %0, %1, %2" : "=v"(uq1) : "v"(qa[nt][2]), "v"(qa[nt][3]));
        *(uint2*)(sb + q * 128 + (xr << 3)) = make_uint2(uq0, uq1);
        *(f32x4*)(sb + 2048 + q * 256 + (xr << 4)) = ka[nt];
        *(f32x4*)(sb + 6144 + q * 256 + (xr << 4)) = va[nt];
    }
    asm volatile("s_waitcnt lgkmcnt(0)" ::: "memory");

    // unit lane: token g, head hp = (lane&15)>>1, pos-half hf = lane&1 (t = 2hf+{0,1})
    const int hp = (lane & 15) >> 1;
    const int hf = lane & 1;
    const int qrow = 4 * g + (hp >> 1);      // staging row for nt = hp>>1
    const int lb = 8 * (hp & 1);             // li-base of this head's 8 d-chans
    f32x2 qq[8], kk01[8], kk23[8];
    #pragma unroll
    for (int d = 0; d < 8; ++d) {
        int xr = (lb + d) ^ (qrow & 7);
        unsigned int uq = *(const unsigned int*)(sb + qrow * 128 + (xr << 3) + 4 * hf);
        qq[d] = (f32x2){bflo(uq), bfhi(uq)};     // (q[d][t0], q[d][t1])
        kk01[d] = *(const f32x2*)(sb + 2048 + qrow * 256 + (xr << 4));
        kk23[d] = *(const f32x2*)(sb + 2048 + qrow * 256 + (xr << 4) + 8);
    }
    // Sp[s] = (S[t0][s], S[t1][s]) via packed FMA, broadcasting K halves
    f32x2 Sp[4];
    PKMUL_LO(Sp[0], qq[0], kk01[0]);
    PKMUL_HI(Sp[1], qq[0], kk01[0]);
    PKMUL_LO(Sp[2], qq[0], kk23[0]);
    PKMUL_HI(Sp[3], qq[0], kk23[0]);
    #pragma unroll
    for (int d = 1; d < 8; ++d) {
        PKFMA_LO(Sp[0], qq[d], kk01[d]);
        PKFMA_HI(Sp[1], qq[d], kk01[d]);
        PKFMA_LO(Sp[2], qq[d], kk23[d]);
        PKFMA_HI(Sp[3], qq[d], kk23[d]);
    }
    // scalar softmax per t (halves of the pairs are individually addressable)
    float P0[4], P1[4];
    {
        float S0[4] = {Sp[0].x, Sp[1].x, Sp[2].x, Sp[3].x};
        float S1[4] = {Sp[0].y, Sp[1].y, Sp[2].y, Sp[3].y};
        float m0 = fmaxf(fmaxf(S0[0], S0[1]), fmaxf(S0[2], S0[3]));
        float m1 = fmaxf(fmaxf(S1[0], S1[1]), fmaxf(S1[2], S1[3]));
        float a0s = __expf((S0[0] - m0) * 0.35355339059327378f);
        float a1s = __expf((S0[1] - m0) * 0.35355339059327378f);
        float a2s = __expf((S0[2] - m0) * 0.35355339059327378f);
        float a3s = __expf((S0[3] - m0) * 0.35355339059327378f);
        float inv0 = 1.0f / (a0s + a1s + a2s + a3s);
        P0[0] = a0s * inv0; P0[1] = a1s * inv0; P0[2] = a2s * inv0; P0[3] = a3s * inv0;
        float b0s = __expf((S1[0] - m1) * 0.35355339059327378f);
        float b1s = __expf((S1[1] - m1) * 0.35355339059327378f);
        float b2s = __expf((S1[2] - m1) * 0.35355339059327378f);
        float b3s = __expf((S1[3] - m1) * 0.35355339059327378f);
        float inv1 = 1.0f / (b0s + b1s + b2s + b3s);
        P1[0] = b0s * inv1; P1[1] = b1s * inv1; P1[2] = b2s * inv1; P1[3] = b3s * inv1;
    }
    f32x2 Pp[4];
    #pragma unroll
    for (int s = 0; s < 4; ++s) Pp[s] = (f32x2){P0[s], P1[s]};

    // O pairs over t: Od[d] = (O[t0][d], O[t1][d]) = sum_s Pp[s] * V[d][s]
    f32x2 Od[8];
    #pragma unroll
    for (int d = 0; d < 8; ++d) {
        int xr = (lb + d) ^ (qrow & 7);
        f32x2 v01 = *(const f32x2*)(sb + 6144 + qrow * 256 + (xr << 4));
        f32x2 v23 = *(const f32x2*)(sb + 6144 + qrow * 256 + (xr << 4) + 8);
        PKMUL_LO(Od[d], Pp[0], v01);
        PKFMA_HI(Od[d], Pp[1], v01);
        PKFMA_LO(Od[d], Pp[2], v23);
        PKFMA_HI(Od[d], Pp[3], v23);
    }
    // O write -> A-frag staging: row r = 4g+2hf+t, chan c = 16*(hp>>1)+8*(hp&1)+d
    #pragma unroll
    for (int t = 0; t < 2; ++t) {
        int r = 4 * g + 2 * hf + t;
        #pragma unroll
        for (int d = 0; d < 8; ++d) {
            float O = Od[d][t];
            unsigned int u;
            asm("v_cvt_pk_bf16_f32 %0, %1, %2" : "=v"(u) : "v"(O), "v"(O));
            int sidx = 4 * (hp & 1) + (d >> 1);
            int boff = 8 * (d & 1) + 2 * (hp >> 1);
            *(unsigned short*)(sb + 128 * r + 16 * (sidx ^ (r & 7)) + boff) = (unsigned short)u;
        }
    }
    asm volatile("s_waitcnt lgkmcnt(0)" ::: "memory");

    // ---- o @ w_o + b_o + residual ----
    get_frags(a0, a1);
    f32x4 oa[4];
    #pragma unroll
    for (int t = 0; t < 4; ++t) oa[t] = z4;
    gemm(a0, a1, Wo, oa);
    {
        float bo[4];
        #pragma unroll
        for (int j = 0; j < 4; ++j) bo[j] = b_o[li + 16 * j];
        #pragma unroll
        for (int i = 0; i < 4; ++i)
            #pragma unroll
            for (int j = 0; j < 4; ++j) x[i][j] += oa[j][i] + bo[j];
    }

    // ---- LN2 + MLP ----
    float h2[4][4];
    lnorm(x, h2, ln2_g, ln2_b);
    put16(h2);
    get_frags(a0, a1);
    f32x4 ma[4];
    #pragma unroll
    for (int t = 0; t < 4; ++t) ma[t] = z4;
    gemm(a0, a1, Wm1, ma);
    float g1[4][4];
    {
        float bm[4];
        #pragma unroll
        for (int j = 0; j < 4; ++j) bm[j] = b_m1[li + 16 * j];
        #pragma unroll
        for (int i = 0; i < 4; ++i)
            #pragma unroll
            for (int j = 0; j < 4; ++j) g1[i][j] = gelu_tanh(ma[j][i] + bm[j]);
    }
    put16(g1);
    get_frags(a0, a1);
    f32x4 m2a[4];
    #pragma unroll
    for (int t = 0; t < 4; ++t) m2a[t] = z4;
    gemm(a0, a1, Wm2, m2a);
    {
        float bm[4];
        #pragma unroll
        for (int j = 0; j < 4; ++j) bm[j] = b_m2[li + 16 * j];
        #pragma unroll
        for (int i = 0; i < 4; ++i)
            #pragma unroll
            for (int j = 0; j < 4; ++j) x[i][j] += m2a[j][i] + bm[j];
    }

    // ---- head softmax over 4 positions; weighted depth blend ----
    float wh[4];
    #pragma unroll
    for (int j = 0; j < 4; ++j) wh[j] = w_head[li + 16 * j];
    float lg[4];
    #pragma unroll
    for (int i = 0; i < 4; ++i) {
        float s = x[i][0] * wh[0] + x[i][1] * wh[1] + x[i][2] * wh[2] + x[i][3] * wh[3];
        #pragma unroll
        for (int m = 1; m < 16; m <<= 1) s += __shfl_xor(s, m, 64);
        lg[i] = s;
    }
    float m = fmaxf(fmaxf(lg[0], lg[1]), fmaxf(lg[2], lg[3]));
    float e0 = __expf(lg[0] - m), e1 = __expf(lg[1] - m);
    float e2 = __expf(lg[2] - m), e3 = __expf(lg[3] - m);
    float p0 = __shfl(predv, gbase + 0, 64);
    float p1 = __shfl(predv, gbase + 1, 64);
    float p2 = __shfl(predv, gbase + 2, 64);
    float p3 = __shfl(predv, gbase + 3, 64);
    float res = (p0 * e0 + p1 * e1 + p2 * e2 + p3 * e3) / (e0 + e1 + e2 + e3);
    if (li == 0) out[n] = res;
}

extern "C" void kernel_launch(void* const* d_in, const int* in_sizes, int n_in,
                              void* d_out, int out_size, void* d_ws, size_t ws_size,
                              hipStream_t stream) {
    const float* depth  = (const float*)d_in[0];
    const float* feat   = (const float*)d_in[1];
    const float* coord  = (const float*)d_in[2];
    const float* w_ce   = (const float*)d_in[3];
    const float* b_ce   = (const float*)d_in[4];
    const float* ln1_g  = (const float*)d_in[5];
    const float* ln1_b  = (const float*)d_in[6];
    const float* w_q    = (const float*)d_in[7];
    const float* w_k    = (const float*)d_in[8];
    const float* w_v    = (const float*)d_in[9];
    const float* w_o    = (const float*)d_in[10];
    const float* b_o    = (const float*)d_in[11];
    const float* ln2_g  = (const float*)d_in[12];
    const float* ln2_b  = (const float*)d_in[13];
    const float* w_m1   = (const float*)d_in[14];
    const float* b_m1   = (const float*)d_in[15];
    const float* w_m2   = (const float*)d_in[16];
    const float* b_m2   = (const float*)d_in[17];
    const float* w_head = (const float*)d_in[18];
    float* outp = (float*)d_out;

    unsigned short* wprep = (unsigned short*)d_ws;
    const size_t FEATT_OFF = 65536;                           // wprep uses 49152 B
    const size_t featT_bytes = (size_t)NB * NHW * 64 * 2;     // bf16
    unsigned int* featT = (unsigned int*)((char*)d_ws + FEATT_OFF);
    bool use_t = (d_ws != nullptr) && (ws_size >= FEATT_OFF + featT_bytes);

    wprep_kernel<<<48, 64, 0, stream>>>(w_q, w_k, w_v, w_o, w_m1, w_m2, wprep);
    if (use_t) {
        feat_transpose_kernel<<<NB * (NHW / 64), 256, 0, stream>>>(feat, featT);
        token_kernel<true><<<NTOK / 16, 256, 0, stream>>>(
            depth, feat, featT, coord, w_ce, b_ce, ln1_g, ln1_b,
            b_o, ln2_g, ln2_b, b_m1, b_m2, w_head, wprep, outp);
    } else {
        token_kernel<false><<<NTOK / 16, 256, 0, stream>>>(
            depth, feat, featT, coord, w_ce, b_ce, ln1_g, ln1_b,
            b_o, ln2_g, ln2_b, b_m1, b_m2, w_head, wprep, outp);
    }
}

// Round 13
// 114.307 us; speedup vs baseline: 1.0543x; 1.0543x over previous
//
#include <hip/hip_runtime.h>
#include <hip/hip_bf16.h>

#define NB 4
#define NQ 32768
#define NHW 65536
#define NTOK (NB * NQ)

typedef __attribute__((ext_vector_type(8))) short short8;   // 8 bf16 = 4 VGPR (MFMA A/B frag)
typedef __attribute__((ext_vector_type(4))) float f32x4;    // MFMA C/D frag
typedef __attribute__((ext_vector_type(2))) float f32x2;    // packed-f32 pair (even-aligned VGPR pair)

// VOP3P packed f32: op_sel selects src half for LOW result, op_sel_hi for HIGH result.
#define PKMUL_LO(dst, a, b) asm("v_pk_mul_f32 %0, %1, %2 op_sel:[0,0] op_sel_hi:[1,0]" : "=v"(dst) : "v"(a), "v"(b))
#define PKMUL_HI(dst, a, b) asm("v_pk_mul_f32 %0, %1, %2 op_sel:[0,1] op_sel_hi:[1,1]" : "=v"(dst) : "v"(a), "v"(b))
#define PKFMA_LO(acc, a, b) asm("v_pk_fma_f32 %0, %1, %2, %0 op_sel:[0,0,0] op_sel_hi:[1,0,1]" : "+v"(acc) : "v"(a), "v"(b))
#define PKFMA_HI(acc, a, b) asm("v_pk_fma_f32 %0, %1, %2, %0 op_sel:[0,1,0] op_sel_hi:[1,1,1]" : "+v"(acc) : "v"(a), "v"(b))

__device__ __forceinline__ unsigned short f2bf(float f) {
    unsigned int u = __float_as_uint(f);
    u = (u + 0x7FFFu + ((u >> 16) & 1u)) >> 16;   // RNE
    return (unsigned short)u;
}

__device__ __forceinline__ float bflo(unsigned int u) { return __uint_as_float(u << 16); }
__device__ __forceinline__ float bfhi(unsigned int u) { return __uint_as_float(u & 0xffff0000u); }

// 16-lane sum-reduce, pure VALU via DPP (no LDS pipe). dpp_ctrl must be a
// compile-time constant -> template parameter.
template<int CTRL>
__device__ __forceinline__ float dpp_add_step(float v) {
    int t = __builtin_amdgcn_update_dpp(0, __float_as_int(v), CTRL, 0xf, 0xf, true);
    return v + __int_as_float(t);
}
__device__ __forceinline__ float sum16(float v) {
    v = dpp_add_step<0xB1>(v);    // quad_perm [1,0,3,2]  (xor 1)
    v = dpp_add_step<0x4E>(v);    // quad_perm [2,3,0,1]  (xor 2)
    v = dpp_add_step<0x141>(v);   // row_half_mirror      (8-group)
    v = dpp_add_step<0x140>(v);   // row_mirror           (16-row)
    return v;
}

__device__ __forceinline__ float gelu_tanh(float u) {
    float z = 0.7978845608028654f * (u + 0.044715f * u * u * u);
    float e = __expf(2.0f * z);
    return u - u / (e + 1.0f);   // 0.5*u*(1+tanh(z)), overflow-safe
}

// (B,C,H,W) f32 -> (B,H*W,64) bf16, channel-permuted: chan c -> position p = 4*(c&15) + (c>>4)
__global__ __launch_bounds__(256) void feat_transpose_kernel(
        const float* __restrict__ feat, unsigned int* __restrict__ featT) {
    __shared__ float tile[64][65];
    int blk = blockIdx.x;
    int b = blk >> 10;
    int hw0 = (blk & 1023) << 6;
    int lane = threadIdx.x & 63;
    int row = threadIdx.x >> 6;
    const float* src = feat + ((size_t)b * 64) * NHW + hw0;
    #pragma unroll
    for (int cc = 0; cc < 16; ++cc) {
        int c = (cc << 2) + row;
        tile[c][lane] = src[(size_t)c * NHW + lane];
    }
    __syncthreads();
    unsigned int* dst = featT + ((size_t)(b * NHW + hw0)) * 32;
    #pragma unroll
    for (int it = 0; it < 8; ++it) {
        int flat = it * 256 + threadIdx.x;
        int w = flat >> 5, pp = flat & 31;        // u32 pp covers positions 2pp,2pp+1
        int c1 = (pp >> 1) + 32 * (pp & 1);       // chan of lo; hi chan = c1+16
        unsigned int u;
        asm("v_cvt_pk_bf16_f32 %0, %1, %2" : "=v"(u) : "v"(tile[c1][w]), "v"(tile[c1 + 16][w]));
        dst[(size_t)w * 32 + pp] = u;
    }
}

// Pack 6 weight matrices (64x64 f32 [k][n]) into bf16 B-fragment order with the
// k' permutation: k' = p, original k = (p&3)*16 + (p>>2).
__global__ __launch_bounds__(64) void wprep_kernel(
        const float* __restrict__ wq, const float* __restrict__ wk,
        const float* __restrict__ wv, const float* __restrict__ wo,
        const float* __restrict__ wm1, const float* __restrict__ wm2,
        unsigned short* __restrict__ out) {
    int bid = blockIdx.x;               // 48
    int mat = bid >> 3, ti = bid & 7;
    int kt = ti >> 2, nt = ti & 3;
    int l = threadIdx.x;
    const float* W = (mat == 0) ? wq : (mat == 1) ? wk : (mat == 2) ? wv
                   : (mat == 3) ? wo : (mat == 4) ? wm1 : wm2;
    unsigned short* dst = out + ((size_t)(bid) * 64 + l) * 8;
    #pragma unroll
    for (int j = 0; j < 8; ++j) {
        int kp = 8 * (l >> 4) + j + 32 * kt;       // permuted k'
        int k = ((kp & 3) << 4) + (kp >> 2);       // original chan
        int n = (l & 15) + 16 * nt;
        dst[j] = f2bf(W[k * 64 + n]);
    }
}

// One wave = 4 tokens (M=16 rows). Lane = (g = lane>>4 token, li = lane&15).
// D-layout: lane holds rows 4g+i, chans li+16*nt (staged at k'-pos 4li+nt).
// Per-wave LDS 10KB: [0,2KB) A-frag staging bf16 (aliases Q attn staging),
//                    [2KB,6KB) K staging f32, [6KB,10KB) V staging f32.
template<bool USE_T>
__global__ __launch_bounds__(256, 2) void token_kernel(
    const float* __restrict__ depth, const float* __restrict__ feat,
    const unsigned int* __restrict__ featT, const float* __restrict__ coord,
    const float* __restrict__ w_ce, const float* __restrict__ b_ce,
    const float* __restrict__ ln1_g, const float* __restrict__ ln1_b,
    const float* __restrict__ b_o, const float* __restrict__ ln2_g,
    const float* __restrict__ ln2_b, const float* __restrict__ b_m1,
    const float* __restrict__ b_m2, const float* __restrict__ w_head,
    const unsigned short* __restrict__ wprep, float* __restrict__ out)
{
    __shared__ char smem[4 * 10240];
    const int wid = threadIdx.x >> 6;
    const int lane = threadIdx.x & 63;
    const int g = lane >> 4;
    const int li = lane & 15;
    const int n = ((blockIdx.x << 2) + wid) * 4 + g;
    const int b = n >> 15;
    char* sb = smem + wid * 10240;

    // ---- distributed gather: each lane computes ONE shifted-coord variant ----
    const float cy0 = coord[2 * n], cx0 = coord[2 * n + 1];
    float relv0, relv1, predv;
    int linv;
    {
        int v = li & 3;
        float vx = (v < 2) ? -1.0f : 1.0f;
        float vy = (v & 1) ? 1.0f : -1.0f;
        float cy = fminf(fmaxf(cy0 + vx * 0.00390625f + 1e-6f, -1.0f + 1e-6f), 1.0f - 1e-6f);
        float cx = fminf(fmaxf(cx0 + vy * 0.00390625f + 1e-6f, -1.0f + 1e-6f), 1.0f - 1e-6f);
        int iy = min(max((int)rintf((cy + 1.0f) * 128.0f - 0.5f), 0), 255);
        int ix = min(max((int)rintf((cx + 1.0f) * 128.0f - 0.5f), 0), 255);
        linv = iy * 256 + ix;
        predv = depth[(b << 16) + linv];
        float ysy = -0.99609375f + 0.0078125f * (float)iy;
        float xsx = -0.99609375f + 0.0078125f * (float)ix;
        relv0 = (cy0 - ysy) * 256.0f;
        relv1 = (cx0 - xsx) * 256.0f;
    }
    const int gbase = lane & 48;     // 16*g

    float wce0[4], wce1[4], bce[4];
    #pragma unroll
    for (int j = 0; j < 4; ++j) {
        wce0[j] = w_ce[li + 16 * j]; wce1[j] = w_ce[64 + li + 16 * j]; bce[j] = b_ce[li + 16 * j];
    }
    float x[4][4];
    #pragma unroll
    for (int i = 0; i < 4; ++i) {
        int lin = __shfl(linv, gbase + i, 64);
        float rel0 = __shfl(relv0, gbase + i, 64);
        float rel1 = __shfl(relv1, gbase + i, 64);
        float t0, t1, t2, t3;
        if (USE_T) {
            uint2 w = *(const uint2*)(featT + ((size_t)((b << 16) + lin)) * 32 + 2 * li);
            t0 = bflo(w.x); t1 = bfhi(w.x); t2 = bflo(w.y); t3 = bfhi(w.y);
        } else {
            t0 = feat[(((size_t)(b * 64 + li)) << 16) + lin];
            t1 = feat[(((size_t)(b * 64 + li + 16)) << 16) + lin];
            t2 = feat[(((size_t)(b * 64 + li + 32)) << 16) + lin];
            t3 = feat[(((size_t)(b * 64 + li + 48)) << 16) + lin];
        }
        x[i][0] = t0 + rel0 * wce0[0] + rel1 * wce1[0] + bce[0];
        x[i][1] = t1 + rel0 * wce0[1] + rel1 * wce1[1] + bce[1];
        x[i][2] = t2 + rel0 * wce0[2] + rel1 * wce1[2] + bce[2];
        x[i][3] = t3 + rel0 * wce0[3] + rel1 * wce1[3] + bce[3];
    }

    // ---- helpers ----
    auto lnorm = [&](float xv[4][4], float hv[4][4],
                     const float* __restrict__ gp, const float* __restrict__ bp) {
        float gj[4], bj[4];
        #pragma unroll
        for (int j = 0; j < 4; ++j) { gj[j] = gp[li + 16 * j]; bj[j] = bp[li + 16 * j]; }
        #pragma unroll
        for (int i = 0; i < 4; ++i) {
            float s4 = (xv[i][0] + xv[i][1]) + (xv[i][2] + xv[i][3]);
            float ss4 = (xv[i][0] * xv[i][0] + xv[i][1] * xv[i][1])
                      + (xv[i][2] * xv[i][2] + xv[i][3] * xv[i][3]);
            float s = sum16(s4);          // DPP all-reduce, no LDS pipe
            float ss = sum16(ss4);
            float mean = s * 0.015625f;
            float var = ss * 0.015625f - mean * mean;
            float rs = rsqrtf(var + 1e-5f);
            #pragma unroll
            for (int j = 0; j < 4; ++j)
                hv[i][j] = (xv[i][j] - mean) * rs * gj[j] + bj[j];
        }
    };

    auto put16 = [&](const float v[4][4]) {
        #pragma unroll
        for (int i = 0; i < 4; ++i) {
            int r = 4 * g + i;
            unsigned int u0, u1;
            asm("v_cvt_pk_bf16_f32 %0, %1, %2" : "=v"(u0) : "v"(v[i][0]), "v"(v[i][1]));
            asm("v_cvt_pk_bf16_f32 %0, %1, %2" : "=v"(u1) : "v"(v[i][2]), "v"(v[i][3]));
            *(uint2*)(sb + 128 * r + 16 * (((li >> 1)) ^ (r & 7)) + 8 * (li & 1))
                = make_uint2(u0, u1);
        }
        asm volatile("s_waitcnt lgkmcnt(0)" ::: "memory");
    };
    auto get_frags = [&](short8& a0, short8& a1) {
        a0 = *(const short8*)(sb + 128 * li + 16 * (g ^ (li & 7)));
        a1 = *(const short8*)(sb + 128 * li + 16 * ((4 + g) ^ (li & 7)));
    };

    auto gemm = [&](short8 a0, short8 a1, const short8* __restrict__ Wf, f32x4 acc[4]) {
        #pragma unroll
        for (int nt = 0; nt < 4; ++nt) {
            acc[nt] = __builtin_amdgcn_mfma_f32_16x16x32_bf16(a0, Wf[nt * 64 + lane], acc[nt], 0, 0, 0);
            acc[nt] = __builtin_amdgcn_mfma_f32_16x16x32_bf16(a1, Wf[(4 + nt) * 64 + lane], acc[nt], 0, 0, 0);
        }
    };

    const short8* Wq  = (const short8*)(wprep);
    const short8* Wk  = (const short8*)(wprep + 1 * 4096);
    const short8* Wv  = (const short8*)(wprep + 2 * 4096);
    const short8* Wo  = (const short8*)(wprep + 3 * 4096);
    const short8* Wm1 = (const short8*)(wprep + 4 * 4096);
    const short8* Wm2 = (const short8*)(wprep + 5 * 4096);
    const f32x4 z4 = {0.0f, 0.0f, 0.0f, 0.0f};

    // ---- LN1 + QKV ----
    float h[4][4];
    lnorm(x, h, ln1_g, ln1_b);
    short8 a0, a1;
    put16(h);
    get_frags(a0, a1);
    f32x4 qa[4], ka[4], va[4];
    #pragma unroll
    for (int t = 0; t < 4; ++t) { qa[t] = z4; ka[t] = z4; va[t] = z4; }
    gemm(a0, a1, Wq, qa);
    gemm(a0, a1, Wk, ka);
    gemm(a0, a1, Wv, va);

    // ---- attention staging: Q bf16 (aliases A-frag region), K/V f32 ----
    #pragma unroll
    for (int nt = 0; nt < 4; ++nt) {
        int q = 4 * g + nt;
        int xr = li ^ (q & 7);
        unsigned int uq0, uq1;
        asm("v_cvt_pk_bf16_f32 %0, %1, %2" : "=v"(uq0) : "v"(qa[nt][0]), "v"(qa[nt][1]));
        asm("v_cvt_pk_bf16_f32 %0, %1, %2" : "=v"(uq1) : "v"(qa[nt][2]), "v"(qa[nt][3]));
        *(uint2*)(sb + q * 128 + (xr << 3)) = make_uint2(uq0, uq1);
        *(f32x4*)(sb + 2048 + q * 256 + (xr << 4)) = ka[nt];
        *(f32x4*)(sb + 6144 + q * 256 + (xr << 4)) = va[nt];
    }
    asm volatile("s_waitcnt lgkmcnt(0)" ::: "memory");

    // unit lane: token g, head hp = (lane&15)>>1, pos-half hf = lane&1 (t = 2hf+{0,1})
    const int hp = (lane & 15) >> 1;
    const int hf = lane & 1;
    const int qrow = 4 * g + (hp >> 1);      // staging row for nt = hp>>1
    const int lb = 8 * (hp & 1);             // li-base of this head's 8 d-chans
    f32x2 qq[8], kk01[8], kk23[8];
    #pragma unroll
    for (int d = 0; d < 8; ++d) {
        int xr = (lb + d) ^ (qrow & 7);
        unsigned int uq = *(const unsigned int*)(sb + qrow * 128 + (xr << 3) + 4 * hf);
        qq[d] = (f32x2){bflo(uq), bfhi(uq)};     // (q[d][t0], q[d][t1])
        kk01[d] = *(const f32x2*)(sb + 2048 + qrow * 256 + (xr << 4));
        kk23[d] = *(const f32x2*)(sb + 2048 + qrow * 256 + (xr << 4) + 8);
    }
    // Sp[s] = (S[t0][s], S[t1][s]) via packed FMA, broadcasting K halves
    f32x2 Sp[4];
    PKMUL_LO(Sp[0], qq[0], kk01[0]);
    PKMUL_HI(Sp[1], qq[0], kk01[0]);
    PKMUL_LO(Sp[2], qq[0], kk23[0]);
    PKMUL_HI(Sp[3], qq[0], kk23[0]);
    #pragma unroll
    for (int d = 1; d < 8; ++d) {
        PKFMA_LO(Sp[0], qq[d], kk01[d]);
        PKFMA_HI(Sp[1], qq[d], kk01[d]);
        PKFMA_LO(Sp[2], qq[d], kk23[d]);
        PKFMA_HI(Sp[3], qq[d], kk23[d]);
    }
    // scalar softmax per t
    float P0[4], P1[4];
    {
        float S0[4] = {Sp[0].x, Sp[1].x, Sp[2].x, Sp[3].x};
        float S1[4] = {Sp[0].y, Sp[1].y, Sp[2].y, Sp[3].y};
        float m0 = fmaxf(fmaxf(S0[0], S0[1]), fmaxf(S0[2], S0[3]));
        float m1 = fmaxf(fmaxf(S1[0], S1[1]), fmaxf(S1[2], S1[3]));
        float a0s = __expf((S0[0] - m0) * 0.35355339059327378f);
        float a1s = __expf((S0[1] - m0) * 0.35355339059327378f);
        float a2s = __expf((S0[2] - m0) * 0.35355339059327378f);
        float a3s = __expf((S0[3] - m0) * 0.35355339059327378f);
        float inv0 = 1.0f / (a0s + a1s + a2s + a3s);
        P0[0] = a0s * inv0; P0[1] = a1s * inv0; P0[2] = a2s * inv0; P0[3] = a3s * inv0;
        float b0s = __expf((S1[0] - m1) * 0.35355339059327378f);
        float b1s = __expf((S1[1] - m1) * 0.35355339059327378f);
        float b2s = __expf((S1[2] - m1) * 0.35355339059327378f);
        float b3s = __expf((S1[3] - m1) * 0.35355339059327378f);
        float inv1 = 1.0f / (b0s + b1s + b2s + b3s);
        P1[0] = b0s * inv1; P1[1] = b1s * inv1; P1[2] = b2s * inv1; P1[3] = b3s * inv1;
    }
    f32x2 Pp[4];
    #pragma unroll
    for (int s = 0; s < 4; ++s) Pp[s] = (f32x2){P0[s], P1[s]};

    // O pairs over t: Od[d] = (O[t0][d], O[t1][d]) = sum_s Pp[s] * V[d][s]
    f32x2 Od[8];
    #pragma unroll
    for (int d = 0; d < 8; ++d) {
        int xr = (lb + d) ^ (qrow & 7);
        f32x2 v01 = *(const f32x2*)(sb + 6144 + qrow * 256 + (xr << 4));
        f32x2 v23 = *(const f32x2*)(sb + 6144 + qrow * 256 + (xr << 4) + 8);
        PKMUL_LO(Od[d], Pp[0], v01);
        PKFMA_HI(Od[d], Pp[1], v01);
        PKFMA_LO(Od[d], Pp[2], v23);
        PKFMA_HI(Od[d], Pp[3], v23);
    }
    // O write -> A-frag staging: row r = 4g+2hf+t, chan c = 16*(hp>>1)+8*(hp&1)+d
    #pragma unroll
    for (int t = 0; t < 2; ++t) {
        int r = 4 * g + 2 * hf + t;
        #pragma unroll
        for (int d = 0; d < 8; ++d) {
            float O = Od[d][t];
            unsigned int u;
            asm("v_cvt_pk_bf16_f32 %0, %1, %2" : "=v"(u) : "v"(O), "v"(O));
            int sidx = 4 * (hp & 1) + (d >> 1);
            int boff = 8 * (d & 1) + 2 * (hp >> 1);
            *(unsigned short*)(sb + 128 * r + 16 * (sidx ^ (r & 7)) + boff) = (unsigned short)u;
        }
    }
    asm volatile("s_waitcnt lgkmcnt(0)" ::: "memory");

    // ---- o @ w_o + b_o + residual ----
    get_frags(a0, a1);
    f32x4 oa[4];
    #pragma unroll
    for (int t = 0; t < 4; ++t) oa[t] = z4;
    gemm(a0, a1, Wo, oa);
    {
        float bo[4];
        #pragma unroll
        for (int j = 0; j < 4; ++j) bo[j] = b_o[li + 16 * j];
        #pragma unroll
        for (int i = 0; i < 4; ++i)
            #pragma unroll
            for (int j = 0; j < 4; ++j) x[i][j] += oa[j][i] + bo[j];
    }

    // ---- LN2 + MLP ----
    float h2[4][4];
    lnorm(x, h2, ln2_g, ln2_b);
    put16(h2);
    get_frags(a0, a1);
    f32x4 ma[4];
    #pragma unroll
    for (int t = 0; t < 4; ++t) ma[t] = z4;
    gemm(a0, a1, Wm1, ma);
    float g1[4][4];
    {
        float bm[4];
        #pragma unroll
        for (int j = 0; j < 4; ++j) bm[j] = b_m1[li + 16 * j];
        #pragma unroll
        for (int i = 0; i < 4; ++i)
            #pragma unroll
            for (int j = 0; j < 4; ++j) g1[i][j] = gelu_tanh(ma[j][i] + bm[j]);
    }
    put16(g1);
    get_frags(a0, a1);
    f32x4 m2a[4];
    #pragma unroll
    for (int t = 0; t < 4; ++t) m2a[t] = z4;
    gemm(a0, a1, Wm2, m2a);
    {
        float bm[4];
        #pragma unroll
        for (int j = 0; j < 4; ++j) bm[j] = b_m2[li + 16 * j];
        #pragma unroll
        for (int i = 0; i < 4; ++i)
            #pragma unroll
            for (int j = 0; j < 4; ++j) x[i][j] += m2a[j][i] + bm[j];
    }

    // ---- head softmax over 4 positions; weighted depth blend ----
    float wh[4];
    #pragma unroll
    for (int j = 0; j < 4; ++j) wh[j] = w_head[li + 16 * j];
    float lg[4];
    #pragma unroll
    for (int i = 0; i < 4; ++i) {
        float s = (x[i][0] * wh[0] + x[i][1] * wh[1]) + (x[i][2] * wh[2] + x[i][3] * wh[3]);
        lg[i] = sum16(s);
    }
    float m = fmaxf(fmaxf(lg[0], lg[1]), fmaxf(lg[2], lg[3]));
    float e0 = __expf(lg[0] - m), e1 = __expf(lg[1] - m);
    float e2 = __expf(lg[2] - m), e3 = __expf(lg[3] - m);
    float p0 = __shfl(predv, gbase + 0, 64);
    float p1 = __shfl(predv, gbase + 1, 64);
    float p2 = __shfl(predv, gbase + 2, 64);
    float p3 = __shfl(predv, gbase + 3, 64);
    float res = (p0 * e0 + p1 * e1 + p2 * e2 + p3 * e3) / (e0 + e1 + e2 + e3);
    if (li == 0) out[n] = res;
}

extern "C" void kernel_launch(void* const* d_in, const int* in_sizes, int n_in,
                              void* d_out, int out_size, void* d_ws, size_t ws_size,
                              hipStream_t stream) {
    const float* depth  = (const float*)d_in[0];
    const float* feat   = (const float*)d_in[1];
    const float* coord  = (const float*)d_in[2];
    const float* w_ce   = (const float*)d_in[3];
    const float* b_ce   = (const float*)d_in[4];
    const float* ln1_g  = (const float*)d_in[5];
    const float* ln1_b  = (const float*)d_in[6];
    const float* w_q    = (const float*)d_in[7];
    const float* w_k    = (const float*)d_in[8];
    const float* w_v    = (const float*)d_in[9];
    const float* w_o    = (const float*)d_in[10];
    const float* b_o    = (const float*)d_in[11];
    const float* ln2_g  = (const float*)d_in[12];
    const float* ln2_b  = (const float*)d_in[13];
    const float* w_m1   = (const float*)d_in[14];
    const float* b_m1   = (const float*)d_in[15];
    const float* w_m2   = (const float*)d_in[16];
    const float* b_m2   = (const float*)d_in[17];
    const float* w_head = (const float*)d_in[18];
    float* outp = (float*)d_out;

    unsigned short* wprep = (unsigned short*)d_ws;
    const size_t FEATT_OFF = 65536;                           // wprep uses 49152 B
    const size_t featT_bytes = (size_t)NB * NHW * 64 * 2;     // bf16
    unsigned int* featT = (unsigned int*)((char*)d_ws + FEATT_OFF);
    bool use_t = (d_ws != nullptr) && (ws_size >= FEATT_OFF + featT_bytes);

    wprep_kernel<<<48, 64, 0, stream>>>(w_q, w_k, w_v, w_o, w_m1, w_m2, wprep);
    if (use_t) {
        feat_transpose_kernel<<<NB * (NHW / 64), 256, 0, stream>>>(feat, featT);
        token_kernel<true><<<NTOK / 16, 256, 0, stream>>>(
            depth, feat, featT, coord, w_ce, b_ce, ln1_g, ln1_b,
            b_o, ln2_g, ln2_b, b_m1, b_m2, w_head, wprep, outp);
    } else {
        token_kernel<false><<<NTOK / 16, 256, 0, stream>>>(
            depth, feat, featT, coord, w_ce, b_ce, ln1_g, ln1_b,
            b_o, ln2_g, ln2_b, b_m1, b_m2, w_head, wprep, outp);
    }
}

// Round 14
// 114.287 us; speedup vs baseline: 1.0545x; 1.0002x over previous
//
#include <hip/hip_runtime.h>
#include <hip/hip_bf16.h>

#define NB 4
#define NQ 32768
#define NHW 65536
#define NTOK (NB * NQ)

typedef __attribute__((ext_vector_type(8))) short short8;   // 8 bf16 = 4 VGPR (MFMA A/B frag)
typedef __attribute__((ext_vector_type(4))) float f32x4;    // MFMA C/D frag
typedef __attribute__((ext_vector_type(2))) float f32x2;    // packed-f32 pair (even-aligned VGPR pair)

// VOP3P packed f32: op_sel selects src half for LOW result, op_sel_hi for HIGH result.
#define PKMUL_LO(dst, a, b) asm("v_pk_mul_f32 %0, %1, %2 op_sel:[0,0] op_sel_hi:[1,0]" : "=v"(dst) : "v"(a), "v"(b))
#define PKMUL_HI(dst, a, b) asm("v_pk_mul_f32 %0, %1, %2 op_sel:[0,1] op_sel_hi:[1,1]" : "=v"(dst) : "v"(a), "v"(b))
#define PKFMA_LO(acc, a, b) asm("v_pk_fma_f32 %0, %1, %2, %0 op_sel:[0,0,0] op_sel_hi:[1,0,1]" : "+v"(acc) : "v"(a), "v"(b))
#define PKFMA_HI(acc, a, b) asm("v_pk_fma_f32 %0, %1, %2, %0 op_sel:[0,1,0] op_sel_hi:[1,1,1]" : "+v"(acc) : "v"(a), "v"(b))

__device__ __forceinline__ unsigned short f2bf(float f) {
    unsigned int u = __float_as_uint(f);
    u = (u + 0x7FFFu + ((u >> 16) & 1u)) >> 16;   // RNE
    return (unsigned short)u;
}

__device__ __forceinline__ float bflo(unsigned int u) { return __uint_as_float(u << 16); }
__device__ __forceinline__ float bfhi(unsigned int u) { return __uint_as_float(u & 0xffff0000u); }

// 16-lane sum-reduce, pure VALU via DPP (no LDS pipe).
template<int CTRL>
__device__ __forceinline__ float dpp_add_step(float v) {
    int t = __builtin_amdgcn_update_dpp(0, __float_as_int(v), CTRL, 0xf, 0xf, true);
    return v + __int_as_float(t);
}
__device__ __forceinline__ float sum16(float v) {
    v = dpp_add_step<0xB1>(v);    // quad_perm [1,0,3,2]  (xor 1)
    v = dpp_add_step<0x4E>(v);    // quad_perm [2,3,0,1]  (xor 2)
    v = dpp_add_step<0x141>(v);   // row_half_mirror      (8-group)
    v = dpp_add_step<0x140>(v);   // row_mirror           (16-row)
    return v;
}

__device__ __forceinline__ float gelu_tanh(float u) {
    float z = 0.7978845608028654f * (u + 0.044715f * u * u * u);
    float e = __expf(2.0f * z);
    return u - u / (e + 1.0f);   // 0.5*u*(1+tanh(z)), overflow-safe
}

// (B,C,H,W) f32 -> (B,H*W,64) bf16, channel-permuted: chan c -> position p = 4*(c&15) + (c>>4)
__global__ __launch_bounds__(256) void feat_transpose_kernel(
        const float* __restrict__ feat, unsigned int* __restrict__ featT) {
    __shared__ float tile[64][65];
    int blk = blockIdx.x;
    int b = blk >> 10;
    int hw0 = (blk & 1023) << 6;
    int lane = threadIdx.x & 63;
    int row = threadIdx.x >> 6;
    const float* src = feat + ((size_t)b * 64) * NHW + hw0;
    #pragma unroll
    for (int cc = 0; cc < 16; ++cc) {
        int c = (cc << 2) + row;
        tile[c][lane] = src[(size_t)c * NHW + lane];
    }
    __syncthreads();
    unsigned int* dst = featT + ((size_t)(b * NHW + hw0)) * 32;
    #pragma unroll
    for (int it = 0; it < 8; ++it) {
        int flat = it * 256 + threadIdx.x;
        int w = flat >> 5, pp = flat & 31;        // u32 pp covers positions 2pp,2pp+1
        int c1 = (pp >> 1) + 32 * (pp & 1);       // chan of lo; hi chan = c1+16
        unsigned int u;
        asm("v_cvt_pk_bf16_f32 %0, %1, %2" : "=v"(u) : "v"(tile[c1][w]), "v"(tile[c1 + 16][w]));
        dst[(size_t)w * 32 + pp] = u;
    }
}

// Pack 6 weight matrices (64x64 f32 [k][n]) into bf16 B-fragment order with the
// k' permutation: k' = p, original k = (p&3)*16 + (p>>2).
__global__ __launch_bounds__(64) void wprep_kernel(
        const float* __restrict__ wq, const float* __restrict__ wk,
        const float* __restrict__ wv, const float* __restrict__ wo,
        const float* __restrict__ wm1, const float* __restrict__ wm2,
        unsigned short* __restrict__ out) {
    int bid = blockIdx.x;               // 48
    int mat = bid >> 3, ti = bid & 7;
    int kt = ti >> 2, nt = ti & 3;
    int l = threadIdx.x;
    const float* W = (mat == 0) ? wq : (mat == 1) ? wk : (mat == 2) ? wv
                   : (mat == 3) ? wo : (mat == 4) ? wm1 : wm2;
    unsigned short* dst = out + ((size_t)(bid) * 64 + l) * 8;
    #pragma unroll
    for (int j = 0; j < 8; ++j) {
        int kp = 8 * (l >> 4) + j + 32 * kt;       // permuted k'
        int k = ((kp & 3) << 4) + (kp >> 2);       // original chan
        int n = (l & 15) + 16 * nt;
        dst[j] = f2bf(W[k * 64 + n]);
    }
}

// One wave = 4 tokens (M=16 rows). Lane = (g = lane>>4 token, li = lane&15).
// D-layout: lane holds rows 4g+i, chans li+16*nt (staged at k'-pos 4li+nt).
// Per-wave LDS 6KB (all bf16): [0,2KB) A-frag staging (aliases Q attn staging),
//                              [2KB,4KB) K staging, [4KB,6KB) V staging.
// QKV gemms are SEQUENCED through one accumulator (peak 16 AGPR, not 48) to
// drop into a higher occupancy register bucket.
template<bool USE_T>
__global__ __launch_bounds__(256, 2) void token_kernel(
    const float* __restrict__ depth, const float* __restrict__ feat,
    const unsigned int* __restrict__ featT, const float* __restrict__ coord,
    const float* __restrict__ w_ce, const float* __restrict__ b_ce,
    const float* __restrict__ ln1_g, const float* __restrict__ ln1_b,
    const float* __restrict__ b_o, const float* __restrict__ ln2_g,
    const float* __restrict__ ln2_b, const float* __restrict__ b_m1,
    const float* __restrict__ b_m2, const float* __restrict__ w_head,
    const unsigned short* __restrict__ wprep, float* __restrict__ out)
{
    __shared__ char smem[4 * 6144];
    const int wid = threadIdx.x >> 6;
    const int lane = threadIdx.x & 63;
    const int g = lane >> 4;
    const int li = lane & 15;
    const int n = ((blockIdx.x << 2) + wid) * 4 + g;
    const int b = n >> 15;
    char* sb = smem + wid * 6144;

    // ---- distributed gather: each lane computes ONE shifted-coord variant ----
    const float cy0 = coord[2 * n], cx0 = coord[2 * n + 1];
    float relv0, relv1, predv;
    int linv;
    {
        int v = li & 3;
        float vx = (v < 2) ? -1.0f : 1.0f;
        float vy = (v & 1) ? 1.0f : -1.0f;
        float cy = fminf(fmaxf(cy0 + vx * 0.00390625f + 1e-6f, -1.0f + 1e-6f), 1.0f - 1e-6f);
        float cx = fminf(fmaxf(cx0 + vy * 0.00390625f + 1e-6f, -1.0f + 1e-6f), 1.0f - 1e-6f);
        int iy = min(max((int)rintf((cy + 1.0f) * 128.0f - 0.5f), 0), 255);
        int ix = min(max((int)rintf((cx + 1.0f) * 128.0f - 0.5f), 0), 255);
        linv = iy * 256 + ix;
        predv = depth[(b << 16) + linv];
        float ysy = -0.99609375f + 0.0078125f * (float)iy;
        float xsx = -0.99609375f + 0.0078125f * (float)ix;
        relv0 = (cy0 - ysy) * 256.0f;
        relv1 = (cx0 - xsx) * 256.0f;
    }
    const int gbase = lane & 48;     // 16*g

    float wce0[4], wce1[4], bce[4];
    #pragma unroll
    for (int j = 0; j < 4; ++j) {
        wce0[j] = w_ce[li + 16 * j]; wce1[j] = w_ce[64 + li + 16 * j]; bce[j] = b_ce[li + 16 * j];
    }
    float x[4][4];
    #pragma unroll
    for (int i = 0; i < 4; ++i) {
        int lin = __shfl(linv, gbase + i, 64);
        float rel0 = __shfl(relv0, gbase + i, 64);
        float rel1 = __shfl(relv1, gbase + i, 64);
        float t0, t1, t2, t3;
        if (USE_T) {
            uint2 w = *(const uint2*)(featT + ((size_t)((b << 16) + lin)) * 32 + 2 * li);
            t0 = bflo(w.x); t1 = bfhi(w.x); t2 = bflo(w.y); t3 = bfhi(w.y);
        } else {
            t0 = feat[(((size_t)(b * 64 + li)) << 16) + lin];
            t1 = feat[(((size_t)(b * 64 + li + 16)) << 16) + lin];
            t2 = feat[(((size_t)(b * 64 + li + 32)) << 16) + lin];
            t3 = feat[(((size_t)(b * 64 + li + 48)) << 16) + lin];
        }
        x[i][0] = t0 + rel0 * wce0[0] + rel1 * wce1[0] + bce[0];
        x[i][1] = t1 + rel0 * wce0[1] + rel1 * wce1[1] + bce[1];
        x[i][2] = t2 + rel0 * wce0[2] + rel1 * wce1[2] + bce[2];
        x[i][3] = t3 + rel0 * wce0[3] + rel1 * wce1[3] + bce[3];
    }

    // ---- helpers ----
    auto lnorm = [&](float xv[4][4], float hv[4][4],
                     const float* __restrict__ gp, const float* __restrict__ bp) {
        float gj[4], bj[4];
        #pragma unroll
        for (int j = 0; j < 4; ++j) { gj[j] = gp[li + 16 * j]; bj[j] = bp[li + 16 * j]; }
        #pragma unroll
        for (int i = 0; i < 4; ++i) {
            float s4 = (xv[i][0] + xv[i][1]) + (xv[i][2] + xv[i][3]);
            float ss4 = (xv[i][0] * xv[i][0] + xv[i][1] * xv[i][1])
                      + (xv[i][2] * xv[i][2] + xv[i][3] * xv[i][3]);
            float s = sum16(s4);          // DPP all-reduce, no LDS pipe
            float ss = sum16(ss4);
            float mean = s * 0.015625f;
            float var = ss * 0.015625f - mean * mean;
            float rs = rsqrtf(var + 1e-5f);
            #pragma unroll
            for (int j = 0; j < 4; ++j)
                hv[i][j] = (xv[i][j] - mean) * rs * gj[j] + bj[j];
        }
    };

    auto put16 = [&](const float v[4][4]) {
        #pragma unroll
        for (int i = 0; i < 4; ++i) {
            int r = 4 * g + i;
            unsigned int u0, u1;
            asm("v_cvt_pk_bf16_f32 %0, %1, %2" : "=v"(u0) : "v"(v[i][0]), "v"(v[i][1]));
            asm("v_cvt_pk_bf16_f32 %0, %1, %2" : "=v"(u1) : "v"(v[i][2]), "v"(v[i][3]));
            *(uint2*)(sb + 128 * r + 16 * (((li >> 1)) ^ (r & 7)) + 8 * (li & 1))
                = make_uint2(u0, u1);
        }
        asm volatile("s_waitcnt lgkmcnt(0)" ::: "memory");
    };
    auto get_frags = [&](short8& a0, short8& a1) {
        a0 = *(const short8*)(sb + 128 * li + 16 * (g ^ (li & 7)));
        a1 = *(const short8*)(sb + 128 * li + 16 * ((4 + g) ^ (li & 7)));
    };

    auto gemm = [&](short8 a0, short8 a1, const short8* __restrict__ Wf, f32x4 acc[4]) {
        #pragma unroll
        for (int nt = 0; nt < 4; ++nt) {
            acc[nt] = __builtin_amdgcn_mfma_f32_16x16x32_bf16(a0, Wf[nt * 64 + lane], acc[nt], 0, 0, 0);
            acc[nt] = __builtin_amdgcn_mfma_f32_16x16x32_bf16(a1, Wf[(4 + nt) * 64 + lane], acc[nt], 0, 0, 0);
        }
    };
    // stage one QKV result (D-layout f32x4 over pos) as bf16 pairs into region `base`
    auto stageQKV = [&](const f32x4 acc[4], int base) {
        #pragma unroll
        for (int nt = 0; nt < 4; ++nt) {
            int q = 4 * g + nt;
            int xr = li ^ (q & 7);
            unsigned int u0, u1;
            asm("v_cvt_pk_bf16_f32 %0, %1, %2" : "=v"(u0) : "v"(acc[nt][0]), "v"(acc[nt][1]));
            asm("v_cvt_pk_bf16_f32 %0, %1, %2" : "=v"(u1) : "v"(acc[nt][2]), "v"(acc[nt][3]));
            *(uint2*)(sb + base + q * 128 + (xr << 3)) = make_uint2(u0, u1);
        }
    };

    const short8* Wq  = (const short8*)(wprep);
    const short8* Wk  = (const short8*)(wprep + 1 * 4096);
    const short8* Wv  = (const short8*)(wprep + 2 * 4096);
    const short8* Wo  = (const short8*)(wprep + 3 * 4096);
    const short8* Wm1 = (const short8*)(wprep + 4 * 4096);
    const short8* Wm2 = (const short8*)(wprep + 5 * 4096);
    const f32x4 z4 = {0.0f, 0.0f, 0.0f, 0.0f};

    // ---- LN1 + QKV (sequenced through ONE accumulator; peak 16 AGPR) ----
    float h[4][4];
    lnorm(x, h, ln1_g, ln1_b);
    short8 a0, a1;
    put16(h);
    get_frags(a0, a1);
    {
        f32x4 acc[4];
        #pragma unroll
        for (int t = 0; t < 4; ++t) acc[t] = z4;
        gemm(a0, a1, Wq, acc);
        stageQKV(acc, 0);        // Q overwrites A-frag staging (h already in a0/a1)
        #pragma unroll
        for (int t = 0; t < 4; ++t) acc[t] = z4;
        gemm(a0, a1, Wk, acc);
        stageQKV(acc, 2048);
        #pragma unroll
        for (int t = 0; t < 4; ++t) acc[t] = z4;
        gemm(a0, a1, Wv, acc);
        stageQKV(acc, 4096);
    }
    asm volatile("s_waitcnt lgkmcnt(0)" ::: "memory");

    // unit lane: token g, head hp = (lane&15)>>1, pos-half hf = lane&1 (t = 2hf+{0,1})
    const int hp = (lane & 15) >> 1;
    const int hf = lane & 1;
    const int qrow = 4 * g + (hp >> 1);      // staging row for nt = hp>>1
    const int lb = 8 * (hp & 1);             // li-base of this head's 8 d-chans
    f32x2 qq[8], kk01[8], kk23[8];
    #pragma unroll
    for (int d = 0; d < 8; ++d) {
        int xr = (lb + d) ^ (qrow & 7);
        unsigned int uq = *(const unsigned int*)(sb + qrow * 128 + (xr << 3) + 4 * hf);
        qq[d] = (f32x2){bflo(uq), bfhi(uq)};     // (q[d][t0], q[d][t1])
        uint2 uk = *(const uint2*)(sb + 2048 + qrow * 128 + (xr << 3));
        kk01[d] = (f32x2){bflo(uk.x), bfhi(uk.x)};
        kk23[d] = (f32x2){bflo(uk.y), bfhi(uk.y)};
    }
    // Sp[s] = (S[t0][s], S[t1][s]) via packed FMA, broadcasting K halves
    f32x2 Sp[4];
    PKMUL_LO(Sp[0], qq[0], kk01[0]);
    PKMUL_HI(Sp[1], qq[0], kk01[0]);
    PKMUL_LO(Sp[2], qq[0], kk23[0]);
    PKMUL_HI(Sp[3], qq[0], kk23[0]);
    #pragma unroll
    for (int d = 1; d < 8; ++d) {
        PKFMA_LO(Sp[0], qq[d], kk01[d]);
        PKFMA_HI(Sp[1], qq[d], kk01[d]);
        PKFMA_LO(Sp[2], qq[d], kk23[d]);
        PKFMA_HI(Sp[3], qq[d], kk23[d]);
    }
    // scalar softmax per t
    float P0[4], P1[4];
    {
        float S0[4] = {Sp[0].x, Sp[1].x, Sp[2].x, Sp[3].x};
        float S1[4] = {Sp[0].y, Sp[1].y, Sp[2].y, Sp[3].y};
        float m0 = fmaxf(fmaxf(S0[0], S0[1]), fmaxf(S0[2], S0[3]));
        float m1 = fmaxf(fmaxf(S1[0], S1[1]), fmaxf(S1[2], S1[3]));
        float a0s = __expf((S0[0] - m0) * 0.35355339059327378f);
        float a1s = __expf((S0[1] - m0) * 0.35355339059327378f);
        float a2s = __expf((S0[2] - m0) * 0.35355339059327378f);
        float a3s = __expf((S0[3] - m0) * 0.35355339059327378f);
        float inv0 = 1.0f / (a0s + a1s + a2s + a3s);
        P0[0] = a0s * inv0; P0[1] = a1s * inv0; P0[2] = a2s * inv0; P0[3] = a3s * inv0;
        float b0s = __expf((S1[0] - m1) * 0.35355339059327378f);
        float b1s = __expf((S1[1] - m1) * 0.35355339059327378f);
        float b2s = __expf((S1[2] - m1) * 0.35355339059327378f);
        float b3s = __expf((S1[3] - m1) * 0.35355339059327378f);
        float inv1 = 1.0f / (b0s + b1s + b2s + b3s);
        P1[0] = b0s * inv1; P1[1] = b1s * inv1; P1[2] = b2s * inv1; P1[3] = b3s * inv1;
    }
    f32x2 Pp[4];
    #pragma unroll
    for (int s = 0; s < 4; ++s) Pp[s] = (f32x2){P0[s], P1[s]};

    // O pairs over t: Od[d] = (O[t0][d], O[t1][d]) = sum_s Pp[s] * V[d][s]
    f32x2 Od[8];
    #pragma unroll
    for (int d = 0; d < 8; ++d) {
        int xr = (lb + d) ^ (qrow & 7);
        uint2 uv = *(const uint2*)(sb + 4096 + qrow * 128 + (xr << 3));
        f32x2 v01 = (f32x2){bflo(uv.x), bfhi(uv.x)};
        f32x2 v23 = (f32x2){bflo(uv.y), bfhi(uv.y)};
        PKMUL_LO(Od[d], Pp[0], v01);
        PKFMA_HI(Od[d], Pp[1], v01);
        PKFMA_LO(Od[d], Pp[2], v23);
        PKFMA_HI(Od[d], Pp[3], v23);
    }
    // O write -> A-frag staging: row r = 4g+2hf+t, chan c = 16*(hp>>1)+8*(hp&1)+d
    #pragma unroll
    for (int t = 0; t < 2; ++t) {
        int r = 4 * g + 2 * hf + t;
        #pragma unroll
        for (int d = 0; d < 8; ++d) {
            float O = Od[d][t];
            unsigned int u;
            asm("v_cvt_pk_bf16_f32 %0, %1, %2" : "=v"(u) : "v"(O), "v"(O));
            int sidx = 4 * (hp & 1) + (d >> 1);
            int boff = 8 * (d & 1) + 2 * (hp >> 1);
            *(unsigned short*)(sb + 128 * r + 16 * (sidx ^ (r & 7)) + boff) = (unsigned short)u;
        }
    }
    asm volatile("s_waitcnt lgkmcnt(0)" ::: "memory");

    // ---- o @ w_o + b_o + residual ----
    get_frags(a0, a1);
    {
        f32x4 oa[4];
        #pragma unroll
        for (int t = 0; t < 4; ++t) oa[t] = z4;
        gemm(a0, a1, Wo, oa);
        float bo[4];
        #pragma unroll
        for (int j = 0; j < 4; ++j) bo[j] = b_o[li + 16 * j];
        #pragma unroll
        for (int i = 0; i < 4; ++i)
            #pragma unroll
            for (int j = 0; j < 4; ++j) x[i][j] += oa[j][i] + bo[j];
    }

    // ---- LN2 + MLP ----
    float h2[4][4];
    lnorm(x, h2, ln2_g, ln2_b);
    put16(h2);
    get_frags(a0, a1);
    float g1[4][4];
    {
        f32x4 ma[4];
        #pragma unroll
        for (int t = 0; t < 4; ++t) ma[t] = z4;
        gemm(a0, a1, Wm1, ma);
        float bm[4];
        #pragma unroll
        for (int j = 0; j < 4; ++j) bm[j] = b_m1[li + 16 * j];
        #pragma unroll
        for (int i = 0; i < 4; ++i)
            #pragma unroll
            for (int j = 0; j < 4; ++j) g1[i][j] = gelu_tanh(ma[j][i] + bm[j]);
    }
    put16(g1);
    get_frags(a0, a1);
    {
        f32x4 m2a[4];
        #pragma unroll
        for (int t = 0; t < 4; ++t) m2a[t] = z4;
        gemm(a0, a1, Wm2, m2a);
        float bm[4];
        #pragma unroll
        for (int j = 0; j < 4; ++j) bm[j] = b_m2[li + 16 * j];
        #pragma unroll
        for (int i = 0; i < 4; ++i)
            #pragma unroll
            for (int j = 0; j < 4; ++j) x[i][j] += m2a[j][i] + bm[j];
    }

    // ---- head softmax over 4 positions; weighted depth blend ----
    float wh[4];
    #pragma unroll
    for (int j = 0; j < 4; ++j) wh[j] = w_head[li + 16 * j];
    float lg[4];
    #pragma unroll
    for (int i = 0; i < 4; ++i) {
        float s = (x[i][0] * wh[0] + x[i][1] * wh[1]) + (x[i][2] * wh[2] + x[i][3] * wh[3]);
        lg[i] = sum16(s);
    }
    float m = fmaxf(fmaxf(lg[0], lg[1]), fmaxf(lg[2], lg[3]));
    float e0 = __expf(lg[0] - m), e1 = __expf(lg[1] - m);
    float e2 = __expf(lg[2] - m), e3 = __expf(lg[3] - m);
    float p0 = __shfl(predv, gbase + 0, 64);
    float p1 = __shfl(predv, gbase + 1, 64);
    float p2 = __shfl(predv, gbase + 2, 64);
    float p3 = __shfl(predv, gbase + 3, 64);
    float res = (p0 * e0 + p1 * e1 + p2 * e2 + p3 * e3) / (e0 + e1 + e2 + e3);
    if (li == 0) out[n] = res;
}

extern "C" void kernel_launch(void* const* d_in, const int* in_sizes, int n_in,
                              void* d_out, int out_size, void* d_ws, size_t ws_size,
                              hipStream_t stream) {
    const float* depth  = (const float*)d_in[0];
    const float* feat   = (const float*)d_in[1];
    const float* coord  = (const float*)d_in[2];
    const float* w_ce   = (const float*)d_in[3];
    const float* b_ce   = (const float*)d_in[4];
    const float* ln1_g  = (const float*)d_in[5];
    const float* ln1_b  = (const float*)d_in[6];
    const float* w_q    = (const float*)d_in[7];
    const float* w_k    = (const float*)d_in[8];
    const float* w_v    = (const float*)d_in[9];
    const float* w_o    = (const float*)d_in[10];
    const float* b_o    = (const float*)d_in[11];
    const float* ln2_g  = (const float*)d_in[12];
    const float* ln2_b  = (const float*)d_in[13];
    const float* w_m1   = (const float*)d_in[14];
    const float* b_m1   = (const float*)d_in[15];
    const float* w_m2   = (const float*)d_in[16];
    const float* b_m2   = (const float*)d_in[17];
    const float* w_head = (const float*)d_in[18];
    float* outp = (float*)d_out;

    unsigned short* wprep = (unsigned short*)d_ws;
    const size_t FEATT_OFF = 65536;                           // wprep uses 49152 B
    const size_t featT_bytes = (size_t)NB * NHW * 64 * 2;     // bf16
    unsigned int* featT = (unsigned int*)((char*)d_ws + FEATT_OFF);
    bool use_t = (d_ws != nullptr) && (ws_size >= FEATT_OFF + featT_bytes);

    wprep_kernel<<<48, 64, 0, stream>>>(w_q, w_k, w_v, w_o, w_m1, w_m2, wprep);
    if (use_t) {
        feat_transpose_kernel<<<NB * (NHW / 64), 256, 0, stream>>>(feat, featT);
        token_kernel<true><<<NTOK / 16, 256, 0, stream>>>(
            depth, feat, featT, coord, w_ce, b_ce, ln1_g, ln1_b,
            b_o, ln2_g, ln2_b, b_m1, b_m2, w_head, wprep, outp);
    } else {
        token_kernel<false><<<NTOK / 16, 256, 0, stream>>>(
            depth, feat, featT, coord, w_ce, b_ce, ln1_g, ln1_b,
            b_o, ln2_g, ln2_b, b_m1, b_m2, w_head, wprep, outp);
    }
}